// Round 14
// baseline (264.649 us; speedup 1.0000x reference)
//
#include <hip/hip_runtime.h>

// mean( (scale*(norms - label))^2 ), scale = 5 if label==1, 3 if label==2, else 1.
// B*S = 4096*8192 = 33,554,432 elements. 268 MB logical read traffic.
//
// R4/R8/R10 (cached): 101us, FETCH 134MB (half L3-served). L3 thrash:
//   268MB working set > 256MB L3.
// R12/R13 (nt both streams): kernel ~80us (~3.35 TB/s, all-HBM reads).
//   Write-only fills hit 6.8 TB/s; copy ceiling 6.29 implies read-stream
//   ~3.15 TB/s -> reads appear limited by per-CU outstanding-miss tracking
//   (~12KB/CU x 900ns ~= 3.4 TB/s), not HBM.
// R14: HYBRID — norms nt (no allocation), labs cached (134MB alone fits L3,
//   no competing allocations -> no thrash; restore writes may leave L3 warm).
//   Splits the two streams across different tracking/latency domains.

#define BLOCK 256

typedef float vf4 __attribute__((ext_vector_type(4)));
typedef int   vi4 __attribute__((ext_vector_type(4)));

__device__ __forceinline__ float sq_term(float n, int l) {
    float s = (l == 1) ? 5.0f : ((l == 2) ? 3.0f : 1.0f);
    float d = s * (n - (float)l);
    return d * d;
}

__global__ __launch_bounds__(BLOCK) void buff_loss_kernel(
        const float* __restrict__ norms,
        const int*   __restrict__ labs,
        float*       __restrict__ out,
        int nvec,            // number of float4/int4 groups
        float inv_n) {
    const vf4* __restrict__ n4 = reinterpret_cast<const vf4*>(norms);
    const vi4* __restrict__ l4 = reinterpret_cast<const vi4*>(labs);

    float acc0 = 0.0f, acc1 = 0.0f, acc2 = 0.0f, acc3 = 0.0f;
    const int tid    = blockIdx.x * blockDim.x + threadIdx.x;
    const int stride = gridDim.x * blockDim.x;

    // 4-way stride unroll; norms nontemporal, labs cached (the ONE change vs R13).
    int i = tid;
    for (; i + 3 * stride < nvec; i += 4 * stride) {
        vf4 na = __builtin_nontemporal_load(n4 + i);
        vf4 nb = __builtin_nontemporal_load(n4 + i + stride);
        vf4 nc = __builtin_nontemporal_load(n4 + i + 2 * stride);
        vf4 nd = __builtin_nontemporal_load(n4 + i + 3 * stride);
        vi4 la = l4[i];
        vi4 lb = l4[i + stride];
        vi4 lc = l4[i + 2 * stride];
        vi4 ld = l4[i + 3 * stride];
        acc0 += sq_term(na.x, la.x) + sq_term(na.y, la.y)
              + sq_term(na.z, la.z) + sq_term(na.w, la.w);
        acc1 += sq_term(nb.x, lb.x) + sq_term(nb.y, lb.y)
              + sq_term(nb.z, lb.z) + sq_term(nb.w, lb.w);
        acc2 += sq_term(nc.x, lc.x) + sq_term(nc.y, lc.y)
              + sq_term(nc.z, lc.z) + sq_term(nc.w, lc.w);
        acc3 += sq_term(nd.x, ld.x) + sq_term(nd.y, ld.y)
              + sq_term(nd.z, ld.z) + sq_term(nd.w, ld.w);
    }
    for (; i < nvec; i += stride) {
        vf4 n = __builtin_nontemporal_load(n4 + i);
        vi4 l = l4[i];
        acc0 += sq_term(n.x, l.x) + sq_term(n.y, l.y)
              + sq_term(n.z, l.z) + sq_term(n.w, l.w);
    }

    float acc = (acc0 + acc1) + (acc2 + acc3);

    // wave64 shuffle reduction
    #pragma unroll
    for (int off = 32; off > 0; off >>= 1)
        acc += __shfl_down(acc, off, 64);

    __shared__ float smem[BLOCK / 64];
    int lane = threadIdx.x & 63;
    int wid  = threadIdx.x >> 6;
    if (lane == 0) smem[wid] = acc;
    __syncthreads();

    if (threadIdx.x == 0) {
        float t = (smem[0] + smem[1]) + (smem[2] + smem[3]);
        atomicAdd(out, t * inv_n);
    }
}

extern "C" void kernel_launch(void* const* d_in, const int* in_sizes, int n_in,
                              void* d_out, int out_size, void* d_ws, size_t ws_size,
                              hipStream_t stream) {
    const float* norms = (const float*)d_in[0];
    const int*   labs  = (const int*)d_in[1];
    float*       out   = (float*)d_out;

    int n    = in_sizes[0];          // 33,554,432 (divisible by 4)
    int nvec = n >> 2;               // float4 groups = 8,388,608
    float inv_n = 1.0f / (float)n;

    // d_out is re-poisoned to 0xAA before every timed call — zero it first.
    hipMemsetAsync(d_out, 0, sizeof(float), stream);

    const int block = BLOCK;
    int grid = (nvec + block - 1) / block;
    if (grid > 2048) grid = 2048;

    buff_loss_kernel<<<grid, block, 0, stream>>>(norms, labs, out, nvec, inv_n);
}